// Round 18
// baseline (144.239 us; speedup 1.0000x reference)
//
#include <hip/hip_runtime.h>
#include <hip/hip_bf16.h>

// MegalodonEMA: 2-pass chunked state-space with MFMA inner chunks.
// Pass1 (VALU): per (seg,b,dtile) Horner sums -> S (bf16), segs 0..2.
// Pass2 (MFMA): block = 16 waves = 16 consecutive d, one segment of 512.
// R18 delta vs R17 (5th consecutive scheduling null -> attack the preserved
// invariant: per-chunk cooperative barrier + LDS output path):
//   (a) x for the WHOLE segment staged once: xbh[16 chunks] bf16 = 128KB
//       (R17's verified transposed+swizzled layout, rolling unroll-4 stage).
//   (b) chunk loop is BARRIER-FREE: xbh read-only; hbq/pclw/kap own-wave
//       in-order LDS; ONE block barrier in the whole kernel.
//   (c) yt + storer role DELETED: silu results stored directly to global in
//       C-layout (lane -> l=ch*32+16hf+4g+r, b=cq, d=wv). 16 waves cover all
//       16 d of each 64B line within a short window -> L2 write-merge.
//   LDS 154KB (xbh 128 + hbq 16 + pclw 8 + kap 2), 1 block/CU.

#define BSZ 8
#define DIM 1024
#define ND 64
#define BD 8192
#define SEGS 4
#define SEGLEN 512
#define CH1 64
#define CPS1 8
#define TD 16
#define XP1 68
#define NCH2 16

typedef short bf16x8 __attribute__((ext_vector_type(8)));
typedef float f32x4 __attribute__((ext_vector_type(4)));
union BF8 { uint32_t u[4]; bf16x8 v; };
#define MFMA __builtin_amdgcn_mfma_f32_16x16x32_bf16

__device__ __forceinline__ uint32_t pk_bf16(float a, float b) {
    __hip_bfloat162 h2 = __float22bfloat162_rn(make_float2(a, b)); // RNE, lo=a
    uint32_t u; __builtin_memcpy(&u, &h2, 4);
    return u;
}

// LDS-only barrier: global loads/stores stay in flight (no vmcnt drain).
__device__ __forceinline__ void block_sync_lds() {
    asm volatile("s_waitcnt lgkmcnt(0)" ::: "memory");
    __builtin_amdgcn_s_barrier();
    asm volatile("" ::: "memory");
}

// ---------------- pass 1: segment Horner sums (VALU; segs 0..2) ----------------
__global__ __launch_bounds__(128, 8) void mega_pass1(
    const float* __restrict__ x,
    const float* __restrict__ dfp,
    const float* __restrict__ cfp,
    ushort* __restrict__ S)
{
    __shared__ float xb[2][TD * XP1];

    const int tid = threadIdx.x;
    const int lane = tid & 63;
    const int wv = tid >> 6;
    const int q   = (lane & 3) | (((lane >> 3) & 1) << 2);
    const int col = wv * 8 + ((lane >> 2) & 1) + ((lane >> 4) & 3) * 2;
    const int blk = blockIdx.x;
    const int dt  = blk & 63;
    const int b   = (blk >> 6) & 7;
    const int seg = blk >> 9;           // 0..2
    const int d   = dt * TD + col;

    float w[8];
    {
        const int pb = d * ND + q * 8;
        const float4 df0 = *(const float4*)(dfp + pb);
        const float4 df1 = *(const float4*)(dfp + pb + 4);
        const float4 cf0 = *(const float4*)(cfp + pb);
        const float4 cf1 = *(const float4*)(cfp + pb + 4);
        const float dfv[8] = {df0.x, df0.y, df0.z, df0.w, df1.x, df1.y, df1.z, df1.w};
        const float cfv[8] = {cf0.x, cf0.y, cf0.z, cf0.w, cf1.x, cf1.y, cf1.z, cf1.w};
        #pragma unroll
        for (int i = 0; i < 8; ++i) {
            const float sd = 1.0f / (1.0f + __expf(-dfv[i]));
            const float sc = 1.0f / (1.0f + __expf(-cfv[i]));
            w[i] = 1.0f - sd * sc;
        }
    }

    const int r0 = tid >> 2;
    const int c4 = (tid & 3) * 4;
    const float* xg = x + (size_t)(seg * SEGLEN) * BD + b * DIM + dt * TD;

    float4 nx0 = *(const float4*)(xg + (size_t)r0 * BD + c4);
    float4 nx1 = *(const float4*)(xg + (size_t)(r0 + 32) * BD + c4);

    float h[8];
    #pragma unroll
    for (int i = 0; i < 8; ++i) h[i] = 0.0f;

    for (int g = 0; g < CPS1; ++g) {
        float* xbuf = xb[g & 1];
        const float nv0[4] = {nx0.x, nx0.y, nx0.z, nx0.w};
        const float nv1[4] = {nx1.x, nx1.y, nx1.z, nx1.w};
        #pragma unroll
        for (int e = 0; e < 4; ++e) {
            xbuf[(c4 + e) * XP1 + r0]      = nv0[e];
            xbuf[(c4 + e) * XP1 + r0 + 32] = nv1[e];
        }
        if (g + 1 < CPS1) {
            nx0 = *(const float4*)(xg + (size_t)((g + 1) * CH1 + r0) * BD + c4);
            nx1 = *(const float4*)(xg + (size_t)((g + 1) * CH1 + r0 + 32) * BD + c4);
        }
        block_sync_lds();

        const float* xcol = xbuf + col * XP1;
        #pragma unroll 2
        for (int t8 = 0; t8 < 8; ++t8) {
            const float4 tva = *(const float4*)(xcol + t8 * 8);
            const float4 tvb = *(const float4*)(xcol + t8 * 8 + 4);
            const float tvs[8] = {tva.x, tva.y, tva.z, tva.w,
                                  tvb.x, tvb.y, tvb.z, tvb.w};
            #pragma unroll
            for (int k = 0; k < 8; ++k) {
                const float xv = tvs[k];
                #pragma unroll
                for (int i = 0; i < 8; ++i) h[i] = fmaf(w[i], h[i], xv);
            }
        }
    }

    const size_t sb = ((size_t)(seg * BSZ + b) * 64 + dt) * 1024 + col * 64 + q * 8;
    uint32_t pk[4] = {pk_bf16(h[0], h[1]), pk_bf16(h[2], h[3]),
                      pk_bf16(h[4], h[5]), pk_bf16(h[6], h[7])};
    *(uint4*)(S + sb) = make_uint4(pk[0], pk[1], pk[2], pk[3]);
}

// ---------------- pass 2: barrier-free MFMA chunk engine ----------------
__global__ __launch_bounds__(1024, 4) void mega_pass2(
    const float* __restrict__ x,
    const float* __restrict__ dfp,
    const float* __restrict__ cfp,
    const float* __restrict__ emp,
    const float* __restrict__ pjp,
    const float* __restrict__ rwp,
    const ushort* __restrict__ S,
    float* __restrict__ out)
{
    __shared__ __align__(16) ushort   xbh[NCH2 * TD * 8 * 32]; // 128 KB bf16
    __shared__ __align__(16) uint32_t hbq[16 * 256];           // 16 KB
    __shared__ __align__(8)  float2   pclw[16 * 64];           // 8 KB
    __shared__ float kap[16 * 32];                             // 2 KB

    const int tid = threadIdx.x;
    const int tl  = tid & 63;
    const int wv  = tid >> 6;          // wave = d-local (0..15)
    const int c   = tl & 15;
    const int g   = tl >> 4;           // 0..3
    const int cq  = c & 7;             // batch col
    const int hf  = c >> 3;            // duplicate-half flag; output Tj = hf
    const int blk = blockIdx.x;
    const int seg = blk >> 6;          // 0..3
    const int dt  = blk & 63;
    const int d0  = dt * TD;
    const int d   = d0 + wv;

    // ---- per-d mode params (lane = n); pclw is own-wave LDS ----
    {
        const int pidx = d * ND + tl;
        const float sd = 1.0f / (1.0f + __expf(-dfp[pidx]));
        const float sc = 1.0f / (1.0f + __expf(-cfp[pidx]));
        const float wn = 1.0f - sd * sc;
        const float cn = sd * emp[pidx] * pjp[pidx] * 0.125f;
        pclw[wv * 64 + tl] = make_float2(cn, log2f(wn));
    }
    const float rwd = rwp[d];

    // ---- stager mapping (R17, verified): thread = (drow, bq, l4g) ----
    const int drow = tid & 15;
    const int bq   = ((tid >> 4) & 1) | (((tid >> 6) & 1) << 1) | (((tid >> 8) & 1) << 2);
    const int l4g  = ((tid >> 5) & 1) | (((tid >> 7) & 1) << 1) | (((tid >> 9) & 1) << 2);
    const int Gst  = l4g >> 1;
    const int Hst  = l4g & 1;
    const int Kst  = ((bq >> 1) & 3) ^ (drow & 3);
    const int xwoff = (drow * 8 + bq) * 32 + ((Gst ^ Kst) << 3) + Hst * 4; // ushort units
    const float* xgs = x + (size_t)(seg * SEGLEN + 4 * l4g) * BD + bq * DIM + d0 + drow;

    // ---- stage the ENTIRE segment (16 chunks, rolling window) ----
    #pragma unroll 4
    for (int ch = 0; ch < NCH2; ++ch) {
        const float* xp = xgs + (size_t)ch * 32 * BD;
        const float a0 = xp[0];
        const float a1 = xp[(size_t)BD];
        const float a2 = xp[(size_t)2 * BD];
        const float a3 = xp[(size_t)3 * BD];
        *(uint2*)(&xbh[ch * 4096 + xwoff]) = make_uint2(pk_bf16(a0, a1), pk_bf16(a2, a3));
    }

    // ---- lane's C-layout mode set: n = 16T + 4g + r ----
    float lw16[16];
    #pragma unroll
    for (int T = 0; T < 4; ++T)
        #pragma unroll
        for (int r = 0; r < 4; ++r)
            lw16[T * 4 + r] = pclw[wv * 64 + 16 * T + 4 * g + r].y;

    // entry state h0 (C layout) from S via w512-Horner
    float h[16];
    #pragma unroll
    for (int i = 0; i < 16; ++i) h[i] = 0.0f;
    if (seg > 0) {
        float w512[16];
        #pragma unroll
        for (int i = 0; i < 16; ++i) w512[i] = exp2f(512.0f * lw16[i]);
        for (int sp = 0; sp < seg; ++sp) {
            const size_t sbase = ((size_t)(sp * BSZ + cq) * 64 + dt) * 1024 + wv * 64;
            #pragma unroll
            for (int T = 0; T < 4; ++T) {
                const uint2 u = *(const uint2*)(S + sbase + 16 * T + 4 * g);
                const float s0 = __uint_as_float(u.x << 16);
                const float s1 = __uint_as_float(u.x & 0xFFFF0000u);
                const float s2 = __uint_as_float(u.y << 16);
                const float s3 = __uint_as_float(u.y & 0xFFFF0000u);
                h[T*4+0] = fmaf(w512[T*4+0], h[T*4+0], s0);
                h[T*4+1] = fmaf(w512[T*4+1], h[T*4+1], s1);
                h[T*4+2] = fmaf(w512[T*4+2], h[T*4+2], s2);
                h[T*4+3] = fmaf(w512[T*4+3], h[T*4+3], s3);
            }
        }
    }
    float w32[16];
    #pragma unroll
    for (int i = 0; i < 16; ++i) w32[i] = exp2f(32.0f * lw16[i]);

    // ---- tables as A-fragments (bf16) ----
    BF8 Vf[4], T2f[2][2], Kf[2];
    #pragma unroll
    for (int T = 0; T < 4; ++T) {               // V[n][m] = w_n^{31-m}
        const float2 pcl = pclw[wv * 64 + 16 * T + c];
        const float winv = exp2f(-pcl.y);
        float ve = exp2f((float)(31 - 8 * g) * pcl.y);
        float vv[8];
        #pragma unroll
        for (int e = 0; e < 8; ++e) { vv[e] = ve; ve *= winv; }
        #pragma unroll
        for (int j = 0; j < 4; ++j) Vf[T].u[j] = pk_bf16(vv[2*j], vv[2*j+1]);
    }
    #pragma unroll
    for (int Tk = 0; Tk < 2; ++Tk) {            // T2[j][n] = c_n w_n^{j+1}
        float2 m8[8];
        #pragma unroll
        for (int e = 0; e < 8; ++e) m8[e] = pclw[wv * 64 + 32 * Tk + 8 * g + e];
        #pragma unroll
        for (int Tj = 0; Tj < 2; ++Tj) {
            const float jf = (float)(16 * Tj + c + 1);
            float tv[8];
            #pragma unroll
            for (int e = 0; e < 8; ++e) tv[e] = m8[e].x * exp2f(jf * m8[e].y);
            #pragma unroll
            for (int j = 0; j < 4; ++j) T2f[Tj][Tk].u[j] = pk_bf16(tv[2*j], tv[2*j+1]);
        }
    }
    {   // kappa[p] = sum_n c_n w_n^p  (own-wave LDS)
        const int p = tl >> 1, half = tl & 1;
        float acc = 0.0f;
        for (int i = 0; i < 32; ++i) {
            const float2 pc = pclw[wv * 64 + half * 32 + i];
            acc = fmaf(pc.x, exp2f((float)p * pc.y), acc);
        }
        const int prt = __builtin_amdgcn_update_dpp(0, __float_as_int(acc), 0xB1, 0xF, 0xF, true);
        acc += __int_as_float(prt);
        if (!half) kap[wv * 32 + p] = acc;
    }
    #pragma unroll
    for (int Tj = 0; Tj < 2; ++Tj) {  // K[j][m] = kappa[j-m] + rwd*(j==m)
        float kv[8];
        #pragma unroll
        for (int e = 0; e < 8; ++e) {
            const int pp = 16 * Tj + c - 8 * g - e;
            float kv_;
            if (pp > 0)       kv_ = kap[wv * 32 + pp];
            else if (pp == 0) kv_ = kap[wv * 32] + rwd;   // diagonal: + residual
            else              kv_ = 0.0f;
            kv[e] = kv_;
        }
        #pragma unroll
        for (int j = 0; j < 4; ++j) Kf[Tj].u[j] = pk_bf16(kv[2*j], kv[2*j+1]);
    }

    // ---- hbq entry write + hB prefetch (own-wave in-order LDS) ----
    const int swzc = ((c & 3) << 3) | (((c >> 2) & 1) << 2);
    uint32_t* hbw = hbq + wv * 256 + cq * 32;
    const f32x4 zf = {0.0f, 0.0f, 0.0f, 0.0f};
    if (hf == 0) {
        #pragma unroll
        for (int T = 0; T < 4; ++T) {
            const int p0 = 8 * T + 2 * g;
            *(uint2*)(&hbw[p0 ^ swzc]) =
                make_uint2(pk_bf16(h[4*T+0], h[4*T+1]), pk_bf16(h[4*T+2], h[4*T+3]));
        }
    }
    BF8 hB0, hB1;
    {
        const uint4 a  = *(const uint4*)(&hbw[(4 * g) ^ swzc]);
        const uint4 b2 = *(const uint4*)(&hbw[(16 + 4 * g) ^ swzc]);
        hB0.u[0]=a.x;  hB0.u[1]=a.y;  hB0.u[2]=a.z;  hB0.u[3]=a.w;
        hB1.u[0]=b2.x; hB1.u[1]=b2.y; hB1.u[2]=b2.z; hB1.u[3]=b2.w;
    }

    // ---- THE single block barrier: x tile staged block-wide ----
    block_sync_lds();

    // ---- barrier-free chunk loop ----
    const int Krd   = ((cq >> 1) & 3) ^ (wv & 3);
    const int xroff = (wv * 8 + cq) * 32 + ((g ^ Krd) << 3);  // ushort units
    // direct C-layout store base: l = seg*512 + ch*32 + 16hf + 4g + r, b = cq, d
    float* ogl = out + (size_t)(seg * SEGLEN + 16 * hf + 4 * g) * BD + cq * DIM + d;

    for (int ch = 0; ch < NCH2; ++ch) {
        // xB fragment: ONE b128 bf16 read from the resident tile
        BF8 xB;
        xB.v = *(const bf16x8*)(&xbh[ch * 4096 + xroff]);

        // y = K@x + T2@h  (carry uses chunk-START h)
        f32x4 y0 = MFMA(Kf[0].v, xB.v, zf, 0, 0, 0);
        f32x4 y1 = MFMA(Kf[1].v, xB.v, zf, 0, 0, 0);
        y0 = MFMA(T2f[0][0].v, hB0.v, y0, 0, 0, 0);
        y1 = MFMA(T2f[1][0].v, hB0.v, y1, 0, 0, 0);
        y0 = MFMA(T2f[0][1].v, hB1.v, y0, 0, 0, 0);
        y1 = MFMA(T2f[1][1].v, hB1.v, y1, 0, 0, 0);
        // U = V@x ; h <- w32*h + U
        #pragma unroll
        for (int T = 0; T < 4; ++T) {
            const f32x4 U = MFMA(Vf[T].v, xB.v, zf, 0, 0, 0);
            h[4*T+0] = fmaf(w32[4*T+0], h[4*T+0], U[0]);
            h[4*T+1] = fmaf(w32[4*T+1], h[4*T+1], U[1]);
            h[4*T+2] = fmaf(w32[4*T+2], h[4*T+2], U[2]);
            h[4*T+3] = fmaf(w32[4*T+3], h[4*T+3], U[3]);
        }
        // write h for NEXT chunk, prefetch next hB (own-wave RAW)
        if (hf == 0) {
            #pragma unroll
            for (int T = 0; T < 4; ++T) {
                const int p0 = 8 * T + 2 * g;
                *(uint2*)(&hbw[p0 ^ swzc]) =
                    make_uint2(pk_bf16(h[4*T+0], h[4*T+1]), pk_bf16(h[4*T+2], h[4*T+3]));
            }
        }
        {
            const uint4 a  = *(const uint4*)(&hbw[(4 * g) ^ swzc]);
            const uint4 b2 = *(const uint4*)(&hbw[(16 + 4 * g) ^ swzc]);
            hB0.u[0]=a.x;  hB0.u[1]=a.y;  hB0.u[2]=a.z;  hB0.u[3]=a.w;
            hB1.u[0]=b2.x; hB1.u[1]=b2.y; hB1.u[2]=b2.z; hB1.u[3]=b2.w;
        }

        // silu + DIRECT global store (C-layout; 16 waves fill each 64B line)
        {
            const f32x4 yy = hf ? y1 : y0;
            float* op = ogl + (size_t)ch * 32 * BD;
            #pragma unroll
            for (int r = 0; r < 4; ++r) {
                const float v = yy[r];
                const float sv = v / (1.0f + __expf(-v));
                op[(size_t)r * BD] = sv;
            }
        }
    }
}

extern "C" void kernel_launch(void* const* d_in, const int* in_sizes, int n_in,
                              void* d_out, int out_size, void* d_ws, size_t ws_size,
                              hipStream_t stream) {
    const float* x  = (const float*)d_in[0];
    const float* df = (const float*)d_in[1];
    const float* cf = (const float*)d_in[2];
    const float* em = (const float*)d_in[3];
    const float* pj = (const float*)d_in[4];
    const float* rw = (const float*)d_in[5];
    float* out = (float*)d_out;
    ushort* S  = (ushort*)d_ws;   // 3*8*64*1024 bf16 = 3.1 MB

    mega_pass1<<<dim3((SEGS - 1) * BSZ * 64), dim3(128), 0, stream>>>(x, df, cf, S);
    mega_pass2<<<dim3(SEGS * 64), dim3(1024), 0, stream>>>(x, df, cf, em, pj, rw, S, out);
}

// Round 20
// 74.019 us; speedup vs baseline: 1.9487x; 1.9487x over previous
//
#include <hip/hip_runtime.h>
#include <hip/hip_bf16.h>

// MegalodonEMA: 2-pass chunked state-space with MFMA inner chunks.
// Pass1 (VALU): per (seg,b,dtile) Horner sums -> S (bf16), segs 0..2.
// Pass2 (MFMA): block = 16 waves = 16 consecutive d, one segment of 512.
//   Per chunk of 32 steps, per wave (one d):
//     U_g  = V @ x_g          (V[n][m] = w_n^{31-m}, 4 mfma)
//     y_g  = K @ x_g + T2 @ h (K[j][m]=kappa[j-m]+rwd*d(j==m), T2[j][n]=c_n w_n^{j+1})
//     h   <- w32 * h + U_g    (16 VALU fma; the only sequential part)
// R20 = R15 verbatim (best passing, 74.7us) + silu via v_rcp_f32 only.
// R19's v_pk_fma_f32 inline asm FAILED correctness: LLVM "v" constraint on
// 64-bit types allocates unaligned VReg_64; CDNA requires even-aligned VGPR
// pairs (v[1:2] invalid) -> garbage w -> recurrence explosion. Lesson: packed
// math only via compiler-generated code, never hand asm with 64-bit "v".
// Structure notes (6 probes, R13-R18, all within +-2% or worse):
//   - lockstep wasn't the stall (R14 2-block split null)
//   - latency hiding exhausted (R15/R16 nulls)
//   - LDS traffic/conflict cuts null (R17)
//   - barrier-free + direct global store REGRESSES 2x (R18: write scatter)
//   => per-chunk barrier + LDS-coalesced output are load-bearing; this is
//      the structure's measured floor (~10K cyc/chunk/CU, no pipe >35%).

#define BSZ 8
#define DIM 1024
#define ND 64
#define BD 8192
#define SEGS 4
#define SEGLEN 512
#define CH1 64
#define CPS1 8
#define TD 16
#define XP1 68
#define NCH2 16
#define YP2 17

typedef short bf16x8 __attribute__((ext_vector_type(8)));
typedef float f32x4 __attribute__((ext_vector_type(4)));
union BF8 { uint32_t u[4]; bf16x8 v; };
#define MFMA __builtin_amdgcn_mfma_f32_16x16x32_bf16

__device__ __forceinline__ uint32_t pk_bf16(float a, float b) {
    __hip_bfloat162 h2 = __float22bfloat162_rn(make_float2(a, b)); // RNE, lo=a
    uint32_t u; __builtin_memcpy(&u, &h2, 4);
    return u;
}

// LDS-only barrier: global loads/stores stay in flight (no vmcnt drain).
__device__ __forceinline__ void block_sync_lds() {
    asm volatile("s_waitcnt lgkmcnt(0)" ::: "memory");
    __builtin_amdgcn_s_barrier();
    asm volatile("" ::: "memory");
}

// ---------------- pass 1: segment Horner sums (VALU; segs 0..2) ----------------
__global__ __launch_bounds__(128, 8) void mega_pass1(
    const float* __restrict__ x,
    const float* __restrict__ dfp,
    const float* __restrict__ cfp,
    ushort* __restrict__ S)
{
    __shared__ float xb[2][TD * XP1];

    const int tid = threadIdx.x;
    const int lane = tid & 63;
    const int wv = tid >> 6;
    const int q   = (lane & 3) | (((lane >> 3) & 1) << 2);
    const int col = wv * 8 + ((lane >> 2) & 1) + ((lane >> 4) & 3) * 2;
    const int blk = blockIdx.x;
    const int dt  = blk & 63;
    const int b   = (blk >> 6) & 7;
    const int seg = blk >> 9;           // 0..2
    const int d   = dt * TD + col;

    float w[8];
    {
        const int pb = d * ND + q * 8;
        const float4 df0 = *(const float4*)(dfp + pb);
        const float4 df1 = *(const float4*)(dfp + pb + 4);
        const float4 cf0 = *(const float4*)(cfp + pb);
        const float4 cf1 = *(const float4*)(cfp + pb + 4);
        const float dfv[8] = {df0.x, df0.y, df0.z, df0.w, df1.x, df1.y, df1.z, df1.w};
        const float cfv[8] = {cf0.x, cf0.y, cf0.z, cf0.w, cf1.x, cf1.y, cf1.z, cf1.w};
        #pragma unroll
        for (int i = 0; i < 8; ++i) {
            const float sd = 1.0f / (1.0f + __expf(-dfv[i]));
            const float sc = 1.0f / (1.0f + __expf(-cfv[i]));
            w[i] = 1.0f - sd * sc;
        }
    }

    const int r0 = tid >> 2;
    const int c4 = (tid & 3) * 4;
    const float* xg = x + (size_t)(seg * SEGLEN) * BD + b * DIM + dt * TD;

    float4 nx0 = *(const float4*)(xg + (size_t)r0 * BD + c4);
    float4 nx1 = *(const float4*)(xg + (size_t)(r0 + 32) * BD + c4);

    float h[8];
    #pragma unroll
    for (int i = 0; i < 8; ++i) h[i] = 0.0f;

    for (int g = 0; g < CPS1; ++g) {
        float* xbuf = xb[g & 1];
        const float nv0[4] = {nx0.x, nx0.y, nx0.z, nx0.w};
        const float nv1[4] = {nx1.x, nx1.y, nx1.z, nx1.w};
        #pragma unroll
        for (int e = 0; e < 4; ++e) {
            xbuf[(c4 + e) * XP1 + r0]      = nv0[e];
            xbuf[(c4 + e) * XP1 + r0 + 32] = nv1[e];
        }
        if (g + 1 < CPS1) {
            nx0 = *(const float4*)(xg + (size_t)((g + 1) * CH1 + r0) * BD + c4);
            nx1 = *(const float4*)(xg + (size_t)((g + 1) * CH1 + r0 + 32) * BD + c4);
        }
        block_sync_lds();

        const float* xcol = xbuf + col * XP1;
        #pragma unroll 2
        for (int t8 = 0; t8 < 8; ++t8) {
            const float4 tva = *(const float4*)(xcol + t8 * 8);
            const float4 tvb = *(const float4*)(xcol + t8 * 8 + 4);
            const float tvs[8] = {tva.x, tva.y, tva.z, tva.w,
                                  tvb.x, tvb.y, tvb.z, tvb.w};
            #pragma unroll
            for (int k = 0; k < 8; ++k) {
                const float xv = tvs[k];
                #pragma unroll
                for (int i = 0; i < 8; ++i) h[i] = fmaf(w[i], h[i], xv);
            }
        }
    }

    const size_t sb = ((size_t)(seg * BSZ + b) * 64 + dt) * 1024 + col * 64 + q * 8;
    uint32_t pk[4] = {pk_bf16(h[0], h[1]), pk_bf16(h[2], h[3]),
                      pk_bf16(h[4], h[5]), pk_bf16(h[6], h[7])};
    *(uint4*)(S + sb) = make_uint4(pk[0], pk[1], pk[2], pk[3]);
}

// ---------------- pass 2: MFMA chunk loop ----------------
__global__ __launch_bounds__(1024, 4) void mega_pass2(
    const float* __restrict__ x,
    const float* __restrict__ dfp,
    const float* __restrict__ cfp,
    const float* __restrict__ emp,
    const float* __restrict__ pjp,
    const float* __restrict__ rwp,
    const ushort* __restrict__ S,
    float* __restrict__ out)
{
    __shared__ __align__(16) float    xb[2][TD * 8 * 36];  // 36864 B
    __shared__ __align__(16) float    yt[2][256 * YP2];    // 34816 B
    __shared__ __align__(16) uint32_t hbq[16 * 256];       // 16384 B
    __shared__ __align__(8)  float2   pclw[16 * 64];       // 8192 B
    __shared__ float kap[16 * 32];                         // 2048 B

    const int tid = threadIdx.x;
    const int tl  = tid & 63;
    const int wv  = tid >> 6;          // wave = d-local (0..15)
    const int c   = tl & 15;
    const int g   = tl >> 4;           // 0..3
    const int cq  = c & 7;             // batch col
    const int hf  = c >> 3;            // duplicate-half flag; epilogue Tj = hf
    const int blk = blockIdx.x;
    const int seg = blk >> 6;          // 0..3
    const int dt  = blk & 63;
    const int d0  = dt * TD;
    const int d   = d0 + wv;

    // ---- per-d mode params (lane = n); per-wave LDS regions ----
    {
        const int pidx = d * ND + tl;
        const float sd = 1.0f / (1.0f + __expf(-dfp[pidx]));
        const float sc = 1.0f / (1.0f + __expf(-cfp[pidx]));
        const float wn = 1.0f - sd * sc;
        const float cn = sd * emp[pidx] * pjp[pidx] * 0.125f;
        pclw[wv * 64 + tl] = make_float2(cn, log2f(wn));
    }
    const float rwd = rwp[d];

    // ---- stager mapping: thread = (drow, bq, l-granule of 4) ----
    const int drow = tid & 15;
    const int bq   = (tid >> 4) & 7;
    const int l4g  = tid >> 7;                         // 0..7
    const int gsw  = 4 * (l4g ^ (drow & 6));           // swizzled word offset
    const int xwoff = (drow * 8 + bq) * 36 + gsw;      // LDS write (16B aligned)
    const float* xgs = x + (size_t)(seg * SEGLEN + 4 * l4g) * BD + bq * DIM + d0 + drow;
    float nx0 = xgs[0];
    float nx1 = xgs[(size_t)BD];
    float nx2 = xgs[(size_t)2 * BD];
    float nx3 = xgs[(size_t)3 * BD];

    // ---- storer mapping ----
    const int rid = tid >> 2;          // 0..255
    const int l_s = rid >> 3;          // 0..31
    const int b_s = rid & 7;
    const int dq  = tid & 3;
    const int yrho = b_s + 8 * ((l_s >> 2) & 3) + 32 * (l_s & 3) + 128 * (l_s >> 4);

    // ---- lane's C-layout mode set: n = 16T + 4g + r ----
    float lw16[16];
    #pragma unroll
    for (int T = 0; T < 4; ++T)
        #pragma unroll
        for (int r = 0; r < 4; ++r)
            lw16[T * 4 + r] = pclw[wv * 64 + 16 * T + 4 * g + r].y;

    // entry state h0 (C layout) from S via w512-Horner
    float h[16];
    #pragma unroll
    for (int i = 0; i < 16; ++i) h[i] = 0.0f;
    if (seg > 0) {
        float w512[16];
        #pragma unroll
        for (int i = 0; i < 16; ++i) w512[i] = exp2f(512.0f * lw16[i]);
        for (int sp = 0; sp < seg; ++sp) {
            const size_t sbase = ((size_t)(sp * BSZ + cq) * 64 + dt) * 1024 + wv * 64;
            #pragma unroll
            for (int T = 0; T < 4; ++T) {
                const uint2 u = *(const uint2*)(S + sbase + 16 * T + 4 * g);
                const float s0 = __uint_as_float(u.x << 16);
                const float s1 = __uint_as_float(u.x & 0xFFFF0000u);
                const float s2 = __uint_as_float(u.y << 16);
                const float s3 = __uint_as_float(u.y & 0xFFFF0000u);
                h[T*4+0] = fmaf(w512[T*4+0], h[T*4+0], s0);
                h[T*4+1] = fmaf(w512[T*4+1], h[T*4+1], s1);
                h[T*4+2] = fmaf(w512[T*4+2], h[T*4+2], s2);
                h[T*4+3] = fmaf(w512[T*4+3], h[T*4+3], s3);
            }
        }
    }
    float w32[16];
    #pragma unroll
    for (int i = 0; i < 16; ++i) w32[i] = exp2f(32.0f * lw16[i]);

    // ---- tables as A-fragments (bf16) ----
    BF8 Vf[4], T2f[2][2], Kf[2];
    #pragma unroll
    for (int T = 0; T < 4; ++T) {               // V[n][m] = w_n^{31-m}
        const float2 pcl = pclw[wv * 64 + 16 * T + c];
        const float winv = exp2f(-pcl.y);
        float ve = exp2f((float)(31 - 8 * g) * pcl.y);
        float vv[8];
        #pragma unroll
        for (int e = 0; e < 8; ++e) { vv[e] = ve; ve *= winv; }
        #pragma unroll
        for (int j = 0; j < 4; ++j) Vf[T].u[j] = pk_bf16(vv[2*j], vv[2*j+1]);
    }
    #pragma unroll
    for (int Tk = 0; Tk < 2; ++Tk) {            // T2[j][n] = c_n w_n^{j+1}
        float2 m8[8];
        #pragma unroll
        for (int e = 0; e < 8; ++e) m8[e] = pclw[wv * 64 + 32 * Tk + 8 * g + e];
        #pragma unroll
        for (int Tj = 0; Tj < 2; ++Tj) {
            const float jf = (float)(16 * Tj + c + 1);
            float tv[8];
            #pragma unroll
            for (int e = 0; e < 8; ++e) tv[e] = m8[e].x * exp2f(jf * m8[e].y);
            #pragma unroll
            for (int j = 0; j < 4; ++j) T2f[Tj][Tk].u[j] = pk_bf16(tv[2*j], tv[2*j+1]);
        }
    }
    {   // kappa[p] = sum_n c_n w_n^p
        const int p = tl >> 1, half = tl & 1;
        float acc = 0.0f;
        for (int i = 0; i < 32; ++i) {
            const float2 pc = pclw[wv * 64 + half * 32 + i];
            acc = fmaf(pc.x, exp2f((float)p * pc.y), acc);
        }
        const int prt = __builtin_amdgcn_update_dpp(0, __float_as_int(acc), 0xB1, 0xF, 0xF, true);
        acc += __int_as_float(prt);             // + lane^1
        if (!half) kap[wv * 32 + p] = acc;
    }
    #pragma unroll
    for (int Tj = 0; Tj < 2; ++Tj) {  // K[j][m] = kappa[j-m] + rwd*(j==m)
        float kv[8];
        #pragma unroll
        for (int e = 0; e < 8; ++e) {
            const int pp = 16 * Tj + c - 8 * g - e;
            float kv_;
            if (pp > 0)       kv_ = kap[wv * 32 + pp];
            else if (pp == 0) kv_ = kap[wv * 32] + rwd;   // diagonal: + residual
            else              kv_ = 0.0f;
            kv[e] = kv_;
        }
        #pragma unroll
        for (int j = 0; j < 4; ++j) Kf[Tj].u[j] = pk_bf16(kv[2*j], kv[2*j+1]);
    }

    // ---- chunk loop (ONE lgkm-only barrier per chunk) ----
    const int sgm = wv & 6;
    const int kb  = 4 * ((2 * g) ^ sgm);        // xB granule base
    const int swzc = ((c & 3) << 3) | (((c >> 2) & 1) << 2); // hbq XOR
    uint32_t* hbw = hbq + wv * 256 + cq * 32;
    float* ogbase = out + (size_t)(seg * SEGLEN) * BD + d0;
    const f32x4 zf = {0.0f, 0.0f, 0.0f, 0.0f};

    // prologue: entry h -> hbq; prefetch hB (own-wave RAW);
    // stage chunk 0 (one b128); prefetch chunk 1
    if (hf == 0) {
        #pragma unroll
        for (int T = 0; T < 4; ++T) {
            const int p0 = 8 * T + 2 * g;
            *(uint2*)(&hbw[p0 ^ swzc]) =
                make_uint2(pk_bf16(h[4*T+0], h[4*T+1]), pk_bf16(h[4*T+2], h[4*T+3]));
        }
    }
    BF8 hB0, hB1;
    {
        const uint4 a  = *(const uint4*)(&hbw[(4 * g) ^ swzc]);
        const uint4 b2 = *(const uint4*)(&hbw[(16 + 4 * g) ^ swzc]);
        hB0.u[0]=a.x;  hB0.u[1]=a.y;  hB0.u[2]=a.z;  hB0.u[3]=a.w;
        hB1.u[0]=b2.x; hB1.u[1]=b2.y; hB1.u[2]=b2.z; hB1.u[3]=b2.w;
    }
    {
        *(float4*)(&xb[0][xwoff]) = make_float4(nx0, nx1, nx2, nx3);
        const float* xp = xgs + (size_t)32 * BD;
        nx0 = xp[0]; nx1 = xp[(size_t)BD]; nx2 = xp[(size_t)2*BD]; nx3 = xp[(size_t)3*BD];
    }
    block_sync_lds();

    for (int ch = 0; ch < NCH2; ++ch) {
        const float* xrow = xb[ch & 1] + (wv * 8 + cq) * 36;

        // xB fragment (k = 8g+e), granule-swizzled
        BF8 xB;
        {
            const float4 fa = *(const float4*)(xrow + kb);
            const float4 fb = *(const float4*)(xrow + kb + 4);
            xB.u[0] = pk_bf16(fa.x, fa.y); xB.u[1] = pk_bf16(fa.z, fa.w);
            xB.u[2] = pk_bf16(fb.x, fb.y); xB.u[3] = pk_bf16(fb.z, fb.w);
        }

        // stage chunk ch+1 (one b128); prefetch ch+2
        if (ch + 1 < NCH2) {
            *(float4*)(&xb[(ch + 1) & 1][xwoff]) = make_float4(nx0, nx1, nx2, nx3);
            if (ch + 2 < NCH2) {
                const float* xp = xgs + (size_t)(ch + 2) * 32 * BD;
                nx0 = xp[0]; nx1 = xp[(size_t)BD]; nx2 = xp[(size_t)2*BD]; nx3 = xp[(size_t)3*BD];
            }
        }
        // store chunk ch-1 from yt[(ch-1)&1]
        if (ch > 0) {
            const float* yprev = yt[(ch - 1) & 1];
            float ov[4];
            #pragma unroll
            for (int e = 0; e < 4; ++e) ov[e] = yprev[yrho * YP2 + 4 * dq + e];
            *(float4*)(ogbase + (size_t)((ch - 1) * 32 + l_s) * BD + b_s * DIM + 4 * dq) =
                make_float4(ov[0], ov[1], ov[2], ov[3]);
        }

        // y = K@x + T2@h  (hB prefetched; carry uses chunk-START h)
        f32x4 y0 = MFMA(Kf[0].v, xB.v, zf, 0, 0, 0);
        f32x4 y1 = MFMA(Kf[1].v, xB.v, zf, 0, 0, 0);
        y0 = MFMA(T2f[0][0].v, hB0.v, y0, 0, 0, 0);
        y1 = MFMA(T2f[1][0].v, hB0.v, y1, 0, 0, 0);
        y0 = MFMA(T2f[0][1].v, hB1.v, y0, 0, 0, 0);
        y1 = MFMA(T2f[1][1].v, hB1.v, y1, 0, 0, 0);
        // U = V@x ; h <- w32*h + U
        #pragma unroll
        for (int T = 0; T < 4; ++T) {
            const f32x4 U = MFMA(Vf[T].v, xB.v, zf, 0, 0, 0);
            h[4*T+0] = fmaf(w32[4*T+0], h[4*T+0], U[0]);
            h[4*T+1] = fmaf(w32[4*T+1], h[4*T+1], U[1]);
            h[4*T+2] = fmaf(w32[4*T+2], h[4*T+2], U[2]);
            h[4*T+3] = fmaf(w32[4*T+3], h[4*T+3], U[3]);
        }
        // write h for NEXT chunk, then prefetch next hB (own-wave RAW;
        // latency hides under epilogue + barrier)
        if (hf == 0) {
            #pragma unroll
            for (int T = 0; T < 4; ++T) {
                const int p0 = 8 * T + 2 * g;
                *(uint2*)(&hbw[p0 ^ swzc]) =
                    make_uint2(pk_bf16(h[4*T+0], h[4*T+1]), pk_bf16(h[4*T+2], h[4*T+3]));
            }
        }
        {
            const uint4 a  = *(const uint4*)(&hbw[(4 * g) ^ swzc]);
            const uint4 b2 = *(const uint4*)(&hbw[(16 + 4 * g) ^ swzc]);
            hB0.u[0]=a.x;  hB0.u[1]=a.y;  hB0.u[2]=a.z;  hB0.u[3]=a.w;
            hB1.u[0]=b2.x; hB1.u[1]=b2.y; hB1.u[2]=b2.z; hB1.u[3]=b2.w;
        }

        // epilogue: silu only (residual folded into K diagonal); rcp not div
        {
            float* ycur = yt[ch & 1];
            const f32x4 yy = hf ? y1 : y0;
            #pragma unroll
            for (int r = 0; r < 4; ++r) {
                const float v = yy[r];
                const float sv = v * __builtin_amdgcn_rcpf(1.0f + __expf(-v));
                ycur[(cq + 8 * (g + 4 * r + 16 * hf)) * YP2 + wv] = sv;
            }
        }
        block_sync_lds();   // xb[(ch+1)&1] staged + yt[ch&1] complete (LDS only)
    }

    // final store: chunk NCH2-1
    {
        const float* yprev = yt[(NCH2 - 1) & 1];
        float ov[4];
        #pragma unroll
        for (int e = 0; e < 4; ++e) ov[e] = yprev[yrho * YP2 + 4 * dq + e];
        *(float4*)(ogbase + (size_t)((NCH2 - 1) * 32 + l_s) * BD + b_s * DIM + 4 * dq) =
            make_float4(ov[0], ov[1], ov[2], ov[3]);
    }
}

extern "C" void kernel_launch(void* const* d_in, const int* in_sizes, int n_in,
                              void* d_out, int out_size, void* d_ws, size_t ws_size,
                              hipStream_t stream) {
    const float* x  = (const float*)d_in[0];
    const float* df = (const float*)d_in[1];
    const float* cf = (const float*)d_in[2];
    const float* em = (const float*)d_in[3];
    const float* pj = (const float*)d_in[4];
    const float* rw = (const float*)d_in[5];
    float* out = (float*)d_out;
    ushort* S  = (ushort*)d_ws;   // 3*8*64*1024 bf16 = 3.1 MB

    mega_pass1<<<dim3((SEGS - 1) * BSZ * 64), dim3(128), 0, stream>>>(x, df, cf, S);
    mega_pass2<<<dim3(SEGS * 64), dim3(1024), 0, stream>>>(x, df, cf, em, pj, rw, S, out);
}

// Round 21
// 73.075 us; speedup vs baseline: 1.9739x; 1.0129x over previous
//
#include <hip/hip_runtime.h>
#include <hip/hip_bf16.h>

// MegalodonEMA: 2-pass chunked state-space with MFMA inner chunks.
// Pass1 (VALU): per (seg,b,dtile) Horner sums -> S (bf16), segs 0..2.
// Pass2 (MFMA): block = 16 waves = 16 consecutive d, one segment of 512.
//   Per chunk of 32 steps, per wave (one d):
//     U_g  = V @ x_g          (V[n][m] = w_n^{31-m}, 4 mfma)
//     y_g  = K @ x_g + T2 @ h (K[j][m]=kappa[j-m]+rwd*d(j==m), T2[j][n]=c_n w_n^{j+1})
//     h   <- w32 * h + U_g    (16 VALU fma; the only sequential part)
// R21 = R20 (best passing, 74.0us) + two zero-risk trims:
//   (a) #pragma unroll 2 on the chunk loop: compile-time ch&1 buffer select,
//       cross-chunk software pipelining headroom for the scheduler.
//   (b) T5 s_setprio(1) around the MFMA cluster (free; null on lockstep per
//       m190, positive where phases give wave role diversity per m218b).
// Structure floor evidence (7 probes R13-R19, all null/regressive):
//   lockstep split null; latency-hiding null; LDS traffic/conflict cuts null;
//   barrier-free + direct store 2x WORSE (write scatter); packed-math asm
//   broke correctness (VGPR pair alignment). d-per-wave MFMA forces the
//   cross-wave LDS I/O transpose (kernel is d-dependent -> N must be batch).

#define BSZ 8
#define DIM 1024
#define ND 64
#define BD 8192
#define SEGS 4
#define SEGLEN 512
#define CH1 64
#define CPS1 8
#define TD 16
#define XP1 68
#define NCH2 16
#define YP2 17

typedef short bf16x8 __attribute__((ext_vector_type(8)));
typedef float f32x4 __attribute__((ext_vector_type(4)));
union BF8 { uint32_t u[4]; bf16x8 v; };
#define MFMA __builtin_amdgcn_mfma_f32_16x16x32_bf16

__device__ __forceinline__ uint32_t pk_bf16(float a, float b) {
    __hip_bfloat162 h2 = __float22bfloat162_rn(make_float2(a, b)); // RNE, lo=a
    uint32_t u; __builtin_memcpy(&u, &h2, 4);
    return u;
}

// LDS-only barrier: global loads/stores stay in flight (no vmcnt drain).
__device__ __forceinline__ void block_sync_lds() {
    asm volatile("s_waitcnt lgkmcnt(0)" ::: "memory");
    __builtin_amdgcn_s_barrier();
    asm volatile("" ::: "memory");
}

// ---------------- pass 1: segment Horner sums (VALU; segs 0..2) ----------------
__global__ __launch_bounds__(128, 8) void mega_pass1(
    const float* __restrict__ x,
    const float* __restrict__ dfp,
    const float* __restrict__ cfp,
    ushort* __restrict__ S)
{
    __shared__ float xb[2][TD * XP1];

    const int tid = threadIdx.x;
    const int lane = tid & 63;
    const int wv = tid >> 6;
    const int q   = (lane & 3) | (((lane >> 3) & 1) << 2);
    const int col = wv * 8 + ((lane >> 2) & 1) + ((lane >> 4) & 3) * 2;
    const int blk = blockIdx.x;
    const int dt  = blk & 63;
    const int b   = (blk >> 6) & 7;
    const int seg = blk >> 9;           // 0..2
    const int d   = dt * TD + col;

    float w[8];
    {
        const int pb = d * ND + q * 8;
        const float4 df0 = *(const float4*)(dfp + pb);
        const float4 df1 = *(const float4*)(dfp + pb + 4);
        const float4 cf0 = *(const float4*)(cfp + pb);
        const float4 cf1 = *(const float4*)(cfp + pb + 4);
        const float dfv[8] = {df0.x, df0.y, df0.z, df0.w, df1.x, df1.y, df1.z, df1.w};
        const float cfv[8] = {cf0.x, cf0.y, cf0.z, cf0.w, cf1.x, cf1.y, cf1.z, cf1.w};
        #pragma unroll
        for (int i = 0; i < 8; ++i) {
            const float sd = 1.0f / (1.0f + __expf(-dfv[i]));
            const float sc = 1.0f / (1.0f + __expf(-cfv[i]));
            w[i] = 1.0f - sd * sc;
        }
    }

    const int r0 = tid >> 2;
    const int c4 = (tid & 3) * 4;
    const float* xg = x + (size_t)(seg * SEGLEN) * BD + b * DIM + dt * TD;

    float4 nx0 = *(const float4*)(xg + (size_t)r0 * BD + c4);
    float4 nx1 = *(const float4*)(xg + (size_t)(r0 + 32) * BD + c4);

    float h[8];
    #pragma unroll
    for (int i = 0; i < 8; ++i) h[i] = 0.0f;

    for (int g = 0; g < CPS1; ++g) {
        float* xbuf = xb[g & 1];
        const float nv0[4] = {nx0.x, nx0.y, nx0.z, nx0.w};
        const float nv1[4] = {nx1.x, nx1.y, nx1.z, nx1.w};
        #pragma unroll
        for (int e = 0; e < 4; ++e) {
            xbuf[(c4 + e) * XP1 + r0]      = nv0[e];
            xbuf[(c4 + e) * XP1 + r0 + 32] = nv1[e];
        }
        if (g + 1 < CPS1) {
            nx0 = *(const float4*)(xg + (size_t)((g + 1) * CH1 + r0) * BD + c4);
            nx1 = *(const float4*)(xg + (size_t)((g + 1) * CH1 + r0 + 32) * BD + c4);
        }
        block_sync_lds();

        const float* xcol = xbuf + col * XP1;
        #pragma unroll 2
        for (int t8 = 0; t8 < 8; ++t8) {
            const float4 tva = *(const float4*)(xcol + t8 * 8);
            const float4 tvb = *(const float4*)(xcol + t8 * 8 + 4);
            const float tvs[8] = {tva.x, tva.y, tva.z, tva.w,
                                  tvb.x, tvb.y, tvb.z, tvb.w};
            #pragma unroll
            for (int k = 0; k < 8; ++k) {
                const float xv = tvs[k];
                #pragma unroll
                for (int i = 0; i < 8; ++i) h[i] = fmaf(w[i], h[i], xv);
            }
        }
    }

    const size_t sb = ((size_t)(seg * BSZ + b) * 64 + dt) * 1024 + col * 64 + q * 8;
    uint32_t pk[4] = {pk_bf16(h[0], h[1]), pk_bf16(h[2], h[3]),
                      pk_bf16(h[4], h[5]), pk_bf16(h[6], h[7])};
    *(uint4*)(S + sb) = make_uint4(pk[0], pk[1], pk[2], pk[3]);
}

// ---------------- pass 2: MFMA chunk loop ----------------
__global__ __launch_bounds__(1024, 4) void mega_pass2(
    const float* __restrict__ x,
    const float* __restrict__ dfp,
    const float* __restrict__ cfp,
    const float* __restrict__ emp,
    const float* __restrict__ pjp,
    const float* __restrict__ rwp,
    const ushort* __restrict__ S,
    float* __restrict__ out)
{
    __shared__ __align__(16) float    xb[2][TD * 8 * 36];  // 36864 B
    __shared__ __align__(16) float    yt[2][256 * YP2];    // 34816 B
    __shared__ __align__(16) uint32_t hbq[16 * 256];       // 16384 B
    __shared__ __align__(8)  float2   pclw[16 * 64];       // 8192 B
    __shared__ float kap[16 * 32];                         // 2048 B

    const int tid = threadIdx.x;
    const int tl  = tid & 63;
    const int wv  = tid >> 6;          // wave = d-local (0..15)
    const int c   = tl & 15;
    const int g   = tl >> 4;           // 0..3
    const int cq  = c & 7;             // batch col
    const int hf  = c >> 3;            // duplicate-half flag; epilogue Tj = hf
    const int blk = blockIdx.x;
    const int seg = blk >> 6;          // 0..3
    const int dt  = blk & 63;
    const int d0  = dt * TD;
    const int d   = d0 + wv;

    // ---- per-d mode params (lane = n); per-wave LDS regions ----
    {
        const int pidx = d * ND + tl;
        const float sd = 1.0f / (1.0f + __expf(-dfp[pidx]));
        const float sc = 1.0f / (1.0f + __expf(-cfp[pidx]));
        const float wn = 1.0f - sd * sc;
        const float cn = sd * emp[pidx] * pjp[pidx] * 0.125f;
        pclw[wv * 64 + tl] = make_float2(cn, log2f(wn));
    }
    const float rwd = rwp[d];

    // ---- stager mapping: thread = (drow, bq, l-granule of 4) ----
    const int drow = tid & 15;
    const int bq   = (tid >> 4) & 7;
    const int l4g  = tid >> 7;                         // 0..7
    const int gsw  = 4 * (l4g ^ (drow & 6));           // swizzled word offset
    const int xwoff = (drow * 8 + bq) * 36 + gsw;      // LDS write (16B aligned)
    const float* xgs = x + (size_t)(seg * SEGLEN + 4 * l4g) * BD + bq * DIM + d0 + drow;
    float nx0 = xgs[0];
    float nx1 = xgs[(size_t)BD];
    float nx2 = xgs[(size_t)2 * BD];
    float nx3 = xgs[(size_t)3 * BD];

    // ---- storer mapping ----
    const int rid = tid >> 2;          // 0..255
    const int l_s = rid >> 3;          // 0..31
    const int b_s = rid & 7;
    const int dq  = tid & 3;
    const int yrho = b_s + 8 * ((l_s >> 2) & 3) + 32 * (l_s & 3) + 128 * (l_s >> 4);

    // ---- lane's C-layout mode set: n = 16T + 4g + r ----
    float lw16[16];
    #pragma unroll
    for (int T = 0; T < 4; ++T)
        #pragma unroll
        for (int r = 0; r < 4; ++r)
            lw16[T * 4 + r] = pclw[wv * 64 + 16 * T + 4 * g + r].y;

    // entry state h0 (C layout) from S via w512-Horner
    float h[16];
    #pragma unroll
    for (int i = 0; i < 16; ++i) h[i] = 0.0f;
    if (seg > 0) {
        float w512[16];
        #pragma unroll
        for (int i = 0; i < 16; ++i) w512[i] = exp2f(512.0f * lw16[i]);
        for (int sp = 0; sp < seg; ++sp) {
            const size_t sbase = ((size_t)(sp * BSZ + cq) * 64 + dt) * 1024 + wv * 64;
            #pragma unroll
            for (int T = 0; T < 4; ++T) {
                const uint2 u = *(const uint2*)(S + sbase + 16 * T + 4 * g);
                const float s0 = __uint_as_float(u.x << 16);
                const float s1 = __uint_as_float(u.x & 0xFFFF0000u);
                const float s2 = __uint_as_float(u.y << 16);
                const float s3 = __uint_as_float(u.y & 0xFFFF0000u);
                h[T*4+0] = fmaf(w512[T*4+0], h[T*4+0], s0);
                h[T*4+1] = fmaf(w512[T*4+1], h[T*4+1], s1);
                h[T*4+2] = fmaf(w512[T*4+2], h[T*4+2], s2);
                h[T*4+3] = fmaf(w512[T*4+3], h[T*4+3], s3);
            }
        }
    }
    float w32[16];
    #pragma unroll
    for (int i = 0; i < 16; ++i) w32[i] = exp2f(32.0f * lw16[i]);

    // ---- tables as A-fragments (bf16) ----
    BF8 Vf[4], T2f[2][2], Kf[2];
    #pragma unroll
    for (int T = 0; T < 4; ++T) {               // V[n][m] = w_n^{31-m}
        const float2 pcl = pclw[wv * 64 + 16 * T + c];
        const float winv = exp2f(-pcl.y);
        float ve = exp2f((float)(31 - 8 * g) * pcl.y);
        float vv[8];
        #pragma unroll
        for (int e = 0; e < 8; ++e) { vv[e] = ve; ve *= winv; }
        #pragma unroll
        for (int j = 0; j < 4; ++j) Vf[T].u[j] = pk_bf16(vv[2*j], vv[2*j+1]);
    }
    #pragma unroll
    for (int Tk = 0; Tk < 2; ++Tk) {            // T2[j][n] = c_n w_n^{j+1}
        float2 m8[8];
        #pragma unroll
        for (int e = 0; e < 8; ++e) m8[e] = pclw[wv * 64 + 32 * Tk + 8 * g + e];
        #pragma unroll
        for (int Tj = 0; Tj < 2; ++Tj) {
            const float jf = (float)(16 * Tj + c + 1);
            float tv[8];
            #pragma unroll
            for (int e = 0; e < 8; ++e) tv[e] = m8[e].x * exp2f(jf * m8[e].y);
            #pragma unroll
            for (int j = 0; j < 4; ++j) T2f[Tj][Tk].u[j] = pk_bf16(tv[2*j], tv[2*j+1]);
        }
    }
    {   // kappa[p] = sum_n c_n w_n^p
        const int p = tl >> 1, half = tl & 1;
        float acc = 0.0f;
        for (int i = 0; i < 32; ++i) {
            const float2 pc = pclw[wv * 64 + half * 32 + i];
            acc = fmaf(pc.x, exp2f((float)p * pc.y), acc);
        }
        const int prt = __builtin_amdgcn_update_dpp(0, __float_as_int(acc), 0xB1, 0xF, 0xF, true);
        acc += __int_as_float(prt);             // + lane^1
        if (!half) kap[wv * 32 + p] = acc;
    }
    #pragma unroll
    for (int Tj = 0; Tj < 2; ++Tj) {  // K[j][m] = kappa[j-m] + rwd*(j==m)
        float kv[8];
        #pragma unroll
        for (int e = 0; e < 8; ++e) {
            const int pp = 16 * Tj + c - 8 * g - e;
            float kv_;
            if (pp > 0)       kv_ = kap[wv * 32 + pp];
            else if (pp == 0) kv_ = kap[wv * 32] + rwd;   // diagonal: + residual
            else              kv_ = 0.0f;
            kv[e] = kv_;
        }
        #pragma unroll
        for (int j = 0; j < 4; ++j) Kf[Tj].u[j] = pk_bf16(kv[2*j], kv[2*j+1]);
    }

    // ---- chunk loop (ONE lgkm-only barrier per chunk; unroll 2) ----
    const int sgm = wv & 6;
    const int kb  = 4 * ((2 * g) ^ sgm);        // xB granule base
    const int swzc = ((c & 3) << 3) | (((c >> 2) & 1) << 2); // hbq XOR
    uint32_t* hbw = hbq + wv * 256 + cq * 32;
    float* ogbase = out + (size_t)(seg * SEGLEN) * BD + d0;
    const f32x4 zf = {0.0f, 0.0f, 0.0f, 0.0f};

    // prologue: entry h -> hbq; prefetch hB (own-wave RAW);
    // stage chunk 0 (one b128); prefetch chunk 1
    if (hf == 0) {
        #pragma unroll
        for (int T = 0; T < 4; ++T) {
            const int p0 = 8 * T + 2 * g;
            *(uint2*)(&hbw[p0 ^ swzc]) =
                make_uint2(pk_bf16(h[4*T+0], h[4*T+1]), pk_bf16(h[4*T+2], h[4*T+3]));
        }
    }
    BF8 hB0, hB1;
    {
        const uint4 a  = *(const uint4*)(&hbw[(4 * g) ^ swzc]);
        const uint4 b2 = *(const uint4*)(&hbw[(16 + 4 * g) ^ swzc]);
        hB0.u[0]=a.x;  hB0.u[1]=a.y;  hB0.u[2]=a.z;  hB0.u[3]=a.w;
        hB1.u[0]=b2.x; hB1.u[1]=b2.y; hB1.u[2]=b2.z; hB1.u[3]=b2.w;
    }
    {
        *(float4*)(&xb[0][xwoff]) = make_float4(nx0, nx1, nx2, nx3);
        const float* xp = xgs + (size_t)32 * BD;
        nx0 = xp[0]; nx1 = xp[(size_t)BD]; nx2 = xp[(size_t)2*BD]; nx3 = xp[(size_t)3*BD];
    }
    block_sync_lds();

    #pragma unroll 2
    for (int ch = 0; ch < NCH2; ++ch) {
        const float* xrow = xb[ch & 1] + (wv * 8 + cq) * 36;

        // xB fragment (k = 8g+e), granule-swizzled
        BF8 xB;
        {
            const float4 fa = *(const float4*)(xrow + kb);
            const float4 fb = *(const float4*)(xrow + kb + 4);
            xB.u[0] = pk_bf16(fa.x, fa.y); xB.u[1] = pk_bf16(fa.z, fa.w);
            xB.u[2] = pk_bf16(fb.x, fb.y); xB.u[3] = pk_bf16(fb.z, fb.w);
        }

        // stage chunk ch+1 (one b128); prefetch ch+2
        if (ch + 1 < NCH2) {
            *(float4*)(&xb[(ch + 1) & 1][xwoff]) = make_float4(nx0, nx1, nx2, nx3);
            if (ch + 2 < NCH2) {
                const float* xp = xgs + (size_t)(ch + 2) * 32 * BD;
                nx0 = xp[0]; nx1 = xp[(size_t)BD]; nx2 = xp[(size_t)2*BD]; nx3 = xp[(size_t)3*BD];
            }
        }
        // store chunk ch-1 from yt[(ch-1)&1]
        if (ch > 0) {
            const float* yprev = yt[(ch - 1) & 1];
            float ov[4];
            #pragma unroll
            for (int e = 0; e < 4; ++e) ov[e] = yprev[yrho * YP2 + 4 * dq + e];
            *(float4*)(ogbase + (size_t)((ch - 1) * 32 + l_s) * BD + b_s * DIM + 4 * dq) =
                make_float4(ov[0], ov[1], ov[2], ov[3]);
        }

        // y = K@x + T2@h  (hB prefetched; carry uses chunk-START h)
        __builtin_amdgcn_s_setprio(1);
        f32x4 y0 = MFMA(Kf[0].v, xB.v, zf, 0, 0, 0);
        f32x4 y1 = MFMA(Kf[1].v, xB.v, zf, 0, 0, 0);
        y0 = MFMA(T2f[0][0].v, hB0.v, y0, 0, 0, 0);
        y1 = MFMA(T2f[1][0].v, hB0.v, y1, 0, 0, 0);
        y0 = MFMA(T2f[0][1].v, hB1.v, y0, 0, 0, 0);
        y1 = MFMA(T2f[1][1].v, hB1.v, y1, 0, 0, 0);
        // U = V@x ; h <- w32*h + U
        #pragma unroll
        for (int T = 0; T < 4; ++T) {
            const f32x4 U = MFMA(Vf[T].v, xB.v, zf, 0, 0, 0);
            h[4*T+0] = fmaf(w32[4*T+0], h[4*T+0], U[0]);
            h[4*T+1] = fmaf(w32[4*T+1], h[4*T+1], U[1]);
            h[4*T+2] = fmaf(w32[4*T+2], h[4*T+2], U[2]);
            h[4*T+3] = fmaf(w32[4*T+3], h[4*T+3], U[3]);
        }
        __builtin_amdgcn_s_setprio(0);
        // write h for NEXT chunk, then prefetch next hB (own-wave RAW;
        // latency hides under epilogue + barrier)
        if (hf == 0) {
            #pragma unroll
            for (int T = 0; T < 4; ++T) {
                const int p0 = 8 * T + 2 * g;
                *(uint2*)(&hbw[p0 ^ swzc]) =
                    make_uint2(pk_bf16(h[4*T+0], h[4*T+1]), pk_bf16(h[4*T+2], h[4*T+3]));
            }
        }
        {
            const uint4 a  = *(const uint4*)(&hbw[(4 * g) ^ swzc]);
            const uint4 b2 = *(const uint4*)(&hbw[(16 + 4 * g) ^ swzc]);
            hB0.u[0]=a.x;  hB0.u[1]=a.y;  hB0.u[2]=a.z;  hB0.u[3]=a.w;
            hB1.u[0]=b2.x; hB1.u[1]=b2.y; hB1.u[2]=b2.z; hB1.u[3]=b2.w;
        }

        // epilogue: silu only (residual folded into K diagonal); rcp not div
        {
            float* ycur = yt[ch & 1];
            const f32x4 yy = hf ? y1 : y0;
            #pragma unroll
            for (int r = 0; r < 4; ++r) {
                const float v = yy[r];
                const float sv = v * __builtin_amdgcn_rcpf(1.0f + __expf(-v));
                ycur[(cq + 8 * (g + 4 * r + 16 * hf)) * YP2 + wv] = sv;
            }
        }
        block_sync_lds();   // xb[(ch+1)&1] staged + yt[ch&1] complete (LDS only)
    }

    // final store: chunk NCH2-1
    {
        const float* yprev = yt[(NCH2 - 1) & 1];
        float ov[4];
        #pragma unroll
        for (int e = 0; e < 4; ++e) ov[e] = yprev[yrho * YP2 + 4 * dq + e];
        *(float4*)(ogbase + (size_t)((NCH2 - 1) * 32 + l_s) * BD + b_s * DIM + 4 * dq) =
            make_float4(ov[0], ov[1], ov[2], ov[3]);
    }
}

extern "C" void kernel_launch(void* const* d_in, const int* in_sizes, int n_in,
                              void* d_out, int out_size, void* d_ws, size_t ws_size,
                              hipStream_t stream) {
    const float* x  = (const float*)d_in[0];
    const float* df = (const float*)d_in[1];
    const float* cf = (const float*)d_in[2];
    const float* em = (const float*)d_in[3];
    const float* pj = (const float*)d_in[4];
    const float* rw = (const float*)d_in[5];
    float* out = (float*)d_out;
    ushort* S  = (ushort*)d_ws;   // 3*8*64*1024 bf16 = 3.1 MB

    mega_pass1<<<dim3((SEGS - 1) * BSZ * 64), dim3(128), 0, stream>>>(x, df, cf, S);
    mega_pass2<<<dim3(SEGS * 64), dim3(1024), 0, stream>>>(x, df, cf, em, pj, rw, S, out);
}